// Round 3
// baseline (3970.333 us; speedup 1.0000x reference)
//
#include <hip/hip_runtime.h>
#include <cstdint>

constexpr int B    = 256;
constexpr int S    = 33;
constexpr int D    = 42;
constexpr int H    = 128;
constexpr int HFF  = 256;
constexpr int T    = 20;
constexpr int NSTEP = S - 1;   // 32
constexpr int DP   = D / 2;    // 21 f16 d-pairs
constexpr int AW   = H * 128;  // A dwords per sample: 128 h x 128 e-pairs = 16384
#define BN_SCALE 0.9999950000374997f

typedef _Float16 h2v __attribute__((ext_vector_type(2)));
union UH2 { uint32_t u; h2v h; };

__device__ __forceinline__ float fdot2u(uint32_t a, uint32_t b, float c) {
    UH2 x, y; x.u = a; y.u = b;
    return __builtin_amdgcn_fdot2(x.h, y.h, c, false);
}
__device__ __forceinline__ uint32_t packh2(float a, float b) {
    UH2 u; u.h = h2v{(_Float16)a, (_Float16)b}; return u.u;
}
__device__ __forceinline__ float gelu_exact(float x) {
    return 0.5f * x * (1.0f + erff(x * 0.70710678118654752f));
}

// ---------------------------------------------------------------------------
// Pack weights (one-time).
//  w0t[j][ip]  (j<256, ip<64) = pair(w0[2ip][j],  w0[2ip+1][j])
//  w1t/w2t[j][ip] (ip<128)    = pair(w1[2ip][j],  w1[2ip+1][j])
//  wq[(h*64+i2)*84 + el*21 + dp] = pair(w3[e][h*D+2dp], w3[e][h*D+2dp+1]),
//      e = 4*i2 + el   (h<128, i2<64, el<4, dp<21)
//  b3p[h*21+dp] = pair(b3[h*42+2dp], b3[h*42+2dp+1])
// ---------------------------------------------------------------------------
__global__ void pack_kernel(const float* __restrict__ w0, const float* __restrict__ w1,
                            const float* __restrict__ w2, const float* __restrict__ w3,
                            const float* __restrict__ b3,
                            uint32_t* __restrict__ w0t, uint32_t* __restrict__ w1t,
                            uint32_t* __restrict__ w2t, uint32_t* __restrict__ wq,
                            uint32_t* __restrict__ b3p) {
    int idx = blockIdx.x * 256 + threadIdx.x;
    if (idx < 256 * 64) {
        int j = idx >> 6, ip = idx & 63;
        w0t[idx] = packh2(w0[(2 * ip) * HFF + j], w0[(2 * ip + 1) * HFF + j]);
    }
    if (idx < 256 * 128) {
        int j = idx >> 7, ip = idx & 127;
        w1t[idx] = packh2(w1[(2 * ip) * HFF + j], w1[(2 * ip + 1) * HFF + j]);
        w2t[idx] = packh2(w2[(2 * ip) * HFF + j], w2[(2 * ip + 1) * HFF + j]);
    }
    if (idx < H * DP) {
        int hh = idx / DP, dp = idx % DP;
        b3p[idx] = packh2(b3[hh * D + 2 * dp], b3[hh * D + 2 * dp + 1]);
    }
    if (idx < 8192 * 84) {
        int hi = idx / 84, r = idx % 84;
        int el = r / 21, dp = r % 21;
        int h = hi >> 6, i2 = hi & 63;
        int e = 4 * i2 + el;
        wq[idx] = packh2(w3[e * (H * D) + h * D + 2 * dp],
                         w3[e * (H * D) + h * D + 2 * dp + 1]);
    }
}

// ---------------------------------------------------------------------------
// Encoder (z0), dxdt f16 pairs, dt.  One block per sample, 128 threads.
// ---------------------------------------------------------------------------
__global__ void prep_kernel(const float* __restrict__ path, const float* __restrict__ ts,
                            const float* __restrict__ ew1, const float* __restrict__ eb1,
                            const float* __restrict__ eg1, const float* __restrict__ ebe1,
                            const float* __restrict__ ew2, const float* __restrict__ eb2,
                            const float* __restrict__ eg2, const float* __restrict__ ebe2,
                            float* __restrict__ zbuf, uint32_t* __restrict__ dxdtp,
                            float* __restrict__ dtb) {
    __shared__ float x0[D], hb[H];
    int b = blockIdx.x, tid = threadIdx.x;
    if (tid < D) x0[tid] = path[b * S * D + tid];
    __syncthreads();
    {
        float acc = eb1[tid];
        for (int d = 0; d < D; ++d) acc += x0[d] * ew1[d * H + tid];
        hb[tid] = gelu_exact(acc * (eg1[tid] * BN_SCALE) + ebe1[tid]);
    }
    __syncthreads();
    {
        float acc = eb2[tid];
        for (int i = 0; i < H; ++i) acc += hb[i] * ew2[i * H + tid];
        zbuf[b * H + tid] = acc * (eg2[tid] * BN_SCALE) + ebe2[tid];
    }
    for (int idx = tid; idx < NSTEP * DP; idx += 128) {
        int s = idx / DP, j = idx % DP;
        float dtv = ts[s + 1] - ts[s];
        int base = b * S * D + s * D + 2 * j;
        float v0 = (path[base + D] - path[base]) / dtv;
        float v1 = (path[base + D + 1] - path[base + 1]) / dtv;
        dxdtp[(s * B + b) * DP + j] = packh2(v0, v1);
    }
    if (b == 0 && tid < NSTEP) dtb[tid] = ts[tid + 1] - ts[tid];
}

// ---------------------------------------------------------------------------
// Fused per-step kernel.
//  blocks [0, eval_blocks): RK4 step s for samples {2c, 2c+1}, c = blockIdx.
//  blocks [eval_blocks, +512): A for step s+1 into Ab_wr (XCD-co-located).
// A layout: Ab[b*AW + h*128 + i], i = e-pair index (contiguous 512B per (b,h)).
// ---------------------------------------------------------------------------
__global__ void __launch_bounds__(256, 3) step_kernel(
    const uint32_t* __restrict__ w0t, const uint32_t* __restrict__ w1t,
    const uint32_t* __restrict__ w2t, const uint32_t* __restrict__ wq,
    const uint32_t* __restrict__ b3p, const uint32_t* __restrict__ dxdtp,
    const float* __restrict__ vb0, const float* __restrict__ vg0, const float* __restrict__ vbe0,
    const float* __restrict__ vb1, const float* __restrict__ vg1, const float* __restrict__ vbe1,
    const float* __restrict__ vb2, const float* __restrict__ vg2, const float* __restrict__ vbe2,
    const float* __restrict__ dtb,
    const uint32_t* __restrict__ Ab_rd, uint32_t* __restrict__ Ab_wr,
    float* __restrict__ zbuf, int s, int eval_blocks) {
    int t = threadIdx.x;

    if ((int)blockIdx.x >= eval_blocks) {
        // ----- A writer for step s+1 -----
        int sa = s + 1;
        if (sa >= NSTEP) return;
        int idx = blockIdx.x - eval_blocks;        // 0..511
        int x = idx & 7;                           // XCD class: samples (b>>1)&7 == x
        int k = idx >> 3;                          // 0..63
        int sub = k & 1;                           // sample half
        int slice = k >> 1;                        // 0..31 -> h = slice*4 + (t>>6)
        int hi = slice * 256 + t;
        int h = hi >> 6, i2 = hi & 63;             // thread owns 4 e-rows (e=4*i2..+3)
        uint32_t wr[84];
        const uint32_t* wp = wq + (size_t)hi * 84;
#pragma unroll
        for (int r = 0; r < 84; ++r) wr[r] = wp[r];
        uint32_t dst_off = h * 128 + i2 * 2;
        for (int n = 0; n < 8; ++n) {
            for (int par = 0; par < 2; ++par) {
                int b = 16 * (sub * 8 + n) + 2 * x + par;
                const uint32_t* dxp = dxdtp + (size_t)(sa * B + b) * DP;
                uint32_t dxr[21];
#pragma unroll
                for (int j = 0; j < 21; ++j) dxr[j] = dxp[j];
                float a0 = 0.f, a1 = 0.f, a2 = 0.f, a3 = 0.f;
#pragma unroll
                for (int j = 0; j < 21; ++j) {
                    a0 = fdot2u(wr[j],      dxr[j], a0);
                    a1 = fdot2u(wr[21 + j], dxr[j], a1);
                    a2 = fdot2u(wr[42 + j], dxr[j], a2);
                    a3 = fdot2u(wr[63 + j], dxr[j], a3);
                }
                uint2 st; st.x = packh2(a0, a1); st.y = packh2(a2, a3);
                *(uint2*)(Ab_wr + (size_t)b * AW + dst_off) = st;
            }
        }
        return;
    }

    // ----- eval: RK4 step s for samples b0, b0+1 -----
    __shared__ uint32_t zzp[128];                  // [s*64 + ip] z f16 pairs
    __shared__ uint32_t yA[256], yB[256], yC[256]; // [s*128 + ip] f16 pairs
    __shared__ float psum[8][256];                 // [s*4+seg][j]
    int c = blockIdx.x, b0 = 2 * c;
    int jt = t & 63, seg = t >> 6;                 // MLP role: 4 j's, K-quarter
    int sC = t >> 7, hC = t & 127;                 // state role: (sample, h)
    float hstep = dtb[s];
    // reducer-role bias regs (j = t)
    float c0b = vb0[t], c0g = vg0[t] * BN_SCALE, c0e = vbe0[t];
    float c1b = vb1[t], c1g = vg1[t] * BN_SCALE, c1e = vbe1[t];
    float c2b = vb2[t], c2g = vg2[t] * BN_SCALE, c2e = vbe2[t];
    // state-role init
    int bC = b0 + sC;
    float zf = zbuf[bC * H + hC];
    float bd3;
    {
        const uint32_t* dxC = dxdtp + (size_t)(s * B + bC) * DP;
        const uint32_t* bp = b3p + hC * DP;
        float q0 = 0.f, q1 = 0.f, q2 = 0.f;
#pragma unroll
        for (int j = 0; j < 21; j += 3) {
            q0 = fdot2u(bp[j], dxC[j], q0);
            q1 = fdot2u(bp[j + 1], dxC[j + 1], q1);
            q2 = fdot2u(bp[j + 2], dxC[j + 2], q2);
        }
        bd3 = q0 + q1 + q2;
    }
    const uint32_t* Arow = Ab_rd + (size_t)bC * AW + hC * 128;
    float ksum = 0.f, kcur = 0.f;

    for (int r = 0; r < 4; ++r) {
        float cin = (r == 0) ? 0.f : ((r == 3) ? 1.f : 0.5f);
        float wsm = (r == 1 || r == 2) ? 2.f : 1.f;
        // state role: write zz (f16)
        ((_Float16*)zzp)[sC * 128 + hC] = (_Float16)(zf + cin * hstep * kcur);
        __syncthreads();
        // ---- L0: 128 -> 256 ----
        {
            float a0[4] = {0.f, 0.f, 0.f, 0.f}, a1[4] = {0.f, 0.f, 0.f, 0.f};
#pragma unroll
            for (int u = 0; u < 4; ++u) {
                int ip = (seg << 4) + (u << 2);
                uint4 y0 = *(const uint4*)&zzp[ip];
                uint4 y1 = *(const uint4*)&zzp[64 + ip];
#pragma unroll
                for (int jl = 0; jl < 4; ++jl) {
                    uint4 w = *(const uint4*)(w0t + ((jt << 2) + jl) * 64 + ip);
                    a0[jl] = fdot2u(w.x, y0.x, a0[jl]); a0[jl] = fdot2u(w.y, y0.y, a0[jl]);
                    a0[jl] = fdot2u(w.z, y0.z, a0[jl]); a0[jl] = fdot2u(w.w, y0.w, a0[jl]);
                    a1[jl] = fdot2u(w.x, y1.x, a1[jl]); a1[jl] = fdot2u(w.y, y1.y, a1[jl]);
                    a1[jl] = fdot2u(w.z, y1.z, a1[jl]); a1[jl] = fdot2u(w.w, y1.w, a1[jl]);
                }
            }
            *(float4*)&psum[seg][jt << 2]     = float4{a0[0], a0[1], a0[2], a0[3]};
            *(float4*)&psum[4 + seg][jt << 2] = float4{a1[0], a1[1], a1[2], a1[3]};
        }
        __syncthreads();
        {
            float v0 = psum[0][t] + psum[1][t] + psum[2][t] + psum[3][t];
            float v1 = psum[4][t] + psum[5][t] + psum[6][t] + psum[7][t];
            ((_Float16*)yA)[t]       = (_Float16)gelu_exact((v0 + c0b) * c0g + c0e);
            ((_Float16*)yA)[256 + t] = (_Float16)gelu_exact((v1 + c0b) * c0g + c0e);
        }
        __syncthreads();
        // ---- L1: 256 -> 256 ----
        {
            float a0[4] = {0.f, 0.f, 0.f, 0.f}, a1[4] = {0.f, 0.f, 0.f, 0.f};
#pragma unroll
            for (int u = 0; u < 8; ++u) {
                int ip = (seg << 5) + (u << 2);
                uint4 y0 = *(const uint4*)&yA[ip];
                uint4 y1 = *(const uint4*)&yA[128 + ip];
#pragma unroll
                for (int jl = 0; jl < 4; ++jl) {
                    uint4 w = *(const uint4*)(w1t + ((jt << 2) + jl) * 128 + ip);
                    a0[jl] = fdot2u(w.x, y0.x, a0[jl]); a0[jl] = fdot2u(w.y, y0.y, a0[jl]);
                    a0[jl] = fdot2u(w.z, y0.z, a0[jl]); a0[jl] = fdot2u(w.w, y0.w, a0[jl]);
                    a1[jl] = fdot2u(w.x, y1.x, a1[jl]); a1[jl] = fdot2u(w.y, y1.y, a1[jl]);
                    a1[jl] = fdot2u(w.z, y1.z, a1[jl]); a1[jl] = fdot2u(w.w, y1.w, a1[jl]);
                }
            }
            *(float4*)&psum[seg][jt << 2]     = float4{a0[0], a0[1], a0[2], a0[3]};
            *(float4*)&psum[4 + seg][jt << 2] = float4{a1[0], a1[1], a1[2], a1[3]};
        }
        __syncthreads();
        {
            float v0 = psum[0][t] + psum[1][t] + psum[2][t] + psum[3][t];
            float v1 = psum[4][t] + psum[5][t] + psum[6][t] + psum[7][t];
            ((_Float16*)yB)[t]       = (_Float16)gelu_exact((v0 + c1b) * c1g + c1e);
            ((_Float16*)yB)[256 + t] = (_Float16)gelu_exact((v1 + c1b) * c1g + c1e);
        }
        __syncthreads();
        // ---- L2: 256 -> 256 ----
        {
            float a0[4] = {0.f, 0.f, 0.f, 0.f}, a1[4] = {0.f, 0.f, 0.f, 0.f};
#pragma unroll
            for (int u = 0; u < 8; ++u) {
                int ip = (seg << 5) + (u << 2);
                uint4 y0 = *(const uint4*)&yB[ip];
                uint4 y1 = *(const uint4*)&yB[128 + ip];
#pragma unroll
                for (int jl = 0; jl < 4; ++jl) {
                    uint4 w = *(const uint4*)(w2t + ((jt << 2) + jl) * 128 + ip);
                    a0[jl] = fdot2u(w.x, y0.x, a0[jl]); a0[jl] = fdot2u(w.y, y0.y, a0[jl]);
                    a0[jl] = fdot2u(w.z, y0.z, a0[jl]); a0[jl] = fdot2u(w.w, y0.w, a0[jl]);
                    a1[jl] = fdot2u(w.x, y1.x, a1[jl]); a1[jl] = fdot2u(w.y, y1.y, a1[jl]);
                    a1[jl] = fdot2u(w.z, y1.z, a1[jl]); a1[jl] = fdot2u(w.w, y1.w, a1[jl]);
                }
            }
            *(float4*)&psum[seg][jt << 2]     = float4{a0[0], a0[1], a0[2], a0[3]};
            *(float4*)&psum[4 + seg][jt << 2] = float4{a1[0], a1[1], a1[2], a1[3]};
        }
        __syncthreads();
        {
            float v0 = psum[0][t] + psum[1][t] + psum[2][t] + psum[3][t];
            float v1 = psum[4][t] + psum[5][t] + psum[6][t] + psum[7][t];
            ((_Float16*)yC)[t]       = (_Float16)gelu_exact((v0 + c2b) * c2g + c2e);
            ((_Float16*)yC)[256 + t] = (_Float16)gelu_exact((v1 + c2b) * c2g + c2e);
        }
        __syncthreads();
        // ---- L3 (state role): kcur[h] = bd3 + sum_i A[bC,h,i] . yC[sC,i] ----
        {
            const uint32_t* ys = yC + (sC << 7);
            float q0 = bd3, q1 = 0.f, q2 = 0.f, q3 = 0.f;
#pragma unroll 8
            for (int u = 0; u < 32; ++u) {
                uint4 aq = *(const uint4*)(Arow + (u << 2));
                uint4 yq = *(const uint4*)&ys[u << 2];
                q0 = fdot2u(aq.x, yq.x, q0); q1 = fdot2u(aq.y, yq.y, q1);
                q2 = fdot2u(aq.z, yq.z, q2); q3 = fdot2u(aq.w, yq.w, q3);
            }
            kcur = (q0 + q1) + (q2 + q3);
            ksum += wsm * kcur;
        }
        __syncthreads();
    }
    zbuf[bC * H + hC] = zf + hstep * (1.f / 6.f) * ksum;
}

// ---------------------------------------------------------------------------
// attended = (zT@wv+bv)@wo+bo.  One block per sample, 128 threads.
// ---------------------------------------------------------------------------
__global__ void att_kernel(const float* __restrict__ zbuf,
                           const float* __restrict__ wv, const float* __restrict__ bv,
                           const float* __restrict__ wo, const float* __restrict__ bo,
                           float* __restrict__ att) {
    __shared__ float zl[H], v[H];
    int b = blockIdx.x, tid = threadIdx.x;
    zl[tid] = zbuf[b * H + tid];
    __syncthreads();
    {
        float acc = bv[tid];
#pragma unroll 8
        for (int i = 0; i < H; ++i) acc += zl[i] * wv[i * H + tid];
        v[tid] = acc;
    }
    __syncthreads();
    {
        float acc = bo[tid];
#pragma unroll 8
        for (int i = 0; i < H; ++i) acc += v[i] * wo[i * H + tid];
        att[b * H + tid] = acc;
    }
}

// ---------------------------------------------------------------------------
// Decoder: one single-wave block per (t, b).  grid = T*B = 5120.
// ---------------------------------------------------------------------------
__global__ void __launch_bounds__(64) dec_kernel(
    const float* __restrict__ att,
    const float* __restrict__ dw1, const float* __restrict__ db1,
    const float* __restrict__ dw2, const float* __restrict__ db2,
    const float* __restrict__ dw3, const float* __restrict__ db3,
    float* __restrict__ out) {
    int bid = blockIdx.x;
    int t = bid >> 8, b = bid & 255;
    int tid = threadIdx.x;
    __shared__ float al[H], h1l[64];
    al[tid] = att[b * H + tid];
    al[tid + 64] = att[b * H + tid + 64];
    __syncthreads();
    {
        float acc = db1[t * 64 + tid];
#pragma unroll 8
        for (int i = 0; i < H; ++i) acc += al[i] * dw1[t * H * 64 + i * 64 + tid];
        h1l[tid] = gelu_exact(acc);
    }
    __syncthreads();
    float v = 0.f;
    if (tid < 32) {
        float acc = db2[t * 32 + tid];
#pragma unroll 8
        for (int i = 0; i < 64; ++i) acc += h1l[i] * dw2[t * 64 * 32 + i * 32 + tid];
        v = gelu_exact(acc) * dw3[t * 32 + tid];
    }
#pragma unroll
    for (int off = 16; off >= 1; off >>= 1) v += __shfl_down(v, off, 64);
    if (tid == 0) out[b * T + t] = 1.f / (1.f + expf(-(v + db3[t])));
}

// ---------------------------------------------------------------------------
extern "C" void kernel_launch(void* const* d_in, const int* in_sizes, int n_in,
                              void* d_out, int out_size, void* d_ws, size_t ws_size,
                              hipStream_t stream) {
    const float* path = (const float*)d_in[0];
    const float* ts   = (const float*)d_in[1];
    const float* ew1  = (const float*)d_in[2];
    const float* eb1  = (const float*)d_in[3];
    const float* eg1  = (const float*)d_in[4];
    const float* ebe1 = (const float*)d_in[5];
    const float* ew2  = (const float*)d_in[6];
    const float* eb2  = (const float*)d_in[7];
    const float* eg2  = (const float*)d_in[8];
    const float* ebe2 = (const float*)d_in[9];
    const float* vw0  = (const float*)d_in[10];
    const float* vb0  = (const float*)d_in[11];
    const float* vg0  = (const float*)d_in[12];
    const float* vbe0 = (const float*)d_in[13];
    const float* vw1  = (const float*)d_in[14];
    const float* vb1  = (const float*)d_in[15];
    const float* vg1  = (const float*)d_in[16];
    const float* vbe1 = (const float*)d_in[17];
    const float* vw2  = (const float*)d_in[18];
    const float* vb2  = (const float*)d_in[19];
    const float* vg2  = (const float*)d_in[20];
    const float* vbe2 = (const float*)d_in[21];
    const float* vw3  = (const float*)d_in[22];
    const float* vb3  = (const float*)d_in[23];
    const float* wv   = (const float*)d_in[24];
    const float* bv   = (const float*)d_in[25];
    const float* wo   = (const float*)d_in[26];
    const float* bo   = (const float*)d_in[27];
    const float* dw1  = (const float*)d_in[28];
    const float* db1  = (const float*)d_in[29];
    const float* dw2  = (const float*)d_in[30];
    const float* db2  = (const float*)d_in[31];
    const float* dw3  = (const float*)d_in[32];
    const float* db3  = (const float*)d_in[33];

    char* ws = (char*)d_ws;
    size_t off = 0;
    auto take = [&](size_t bytes) { char* p = ws + off; off += (bytes + 255) & ~(size_t)255; return p; };
    uint32_t* Ab0   = (uint32_t*)take((size_t)B * AW * 4);          // 16.78 MB
    uint32_t* Ab1   = (uint32_t*)take((size_t)B * AW * 4);          // 16.78 MB
    uint32_t* dxdtp = (uint32_t*)take((size_t)NSTEP * B * DP * 4);  // 688 KB
    float*    dtb   = (float*)take(NSTEP * 4);
    float*    zbuf  = (float*)take((size_t)B * H * 4);
    float*    att   = (float*)take((size_t)B * H * 4);
    uint32_t* w0t   = (uint32_t*)take((size_t)256 * 64 * 4);
    uint32_t* w1t   = (uint32_t*)take((size_t)256 * 128 * 4);
    uint32_t* w2t   = (uint32_t*)take((size_t)256 * 128 * 4);
    uint32_t* wq    = (uint32_t*)take((size_t)8192 * 84 * 4);       // 2.75 MB
    uint32_t* b3p   = (uint32_t*)take((size_t)H * DP * 4);

    pack_kernel<<<(8192 * 84 + 255) / 256, 256, 0, stream>>>(vw0, vw1, vw2, vw3, vb3,
                                                             w0t, w1t, w2t, wq, b3p);
    prep_kernel<<<B, 128, 0, stream>>>(path, ts, ew1, eb1, eg1, ebe1,
                                       ew2, eb2, eg2, ebe2, zbuf, dxdtp, dtb);
    // initial A for step 0 (writer only)
    step_kernel<<<512, 256, 0, stream>>>(w0t, w1t, w2t, wq, b3p, dxdtp,
                                         vb0, vg0, vbe0, vb1, vg1, vbe1, vb2, vg2, vbe2,
                                         dtb, Ab1, Ab0, zbuf, -1, 0);
    for (int s = 0; s < NSTEP; ++s) {
        const uint32_t* rd = (s & 1) ? Ab1 : Ab0;
        uint32_t*       wr = (s & 1) ? Ab0 : Ab1;
        int grid = (s < NSTEP - 1) ? (128 + 512) : 128;
        step_kernel<<<grid, 256, 0, stream>>>(w0t, w1t, w2t, wq, b3p, dxdtp,
                                              vb0, vg0, vbe0, vb1, vg1, vbe1, vb2, vg2, vbe2,
                                              dtb, rd, wr, zbuf, s, 128);
    }
    att_kernel<<<B, 128, 0, stream>>>(zbuf, wv, bv, wo, bo, att);
    dec_kernel<<<T * B, 64, 0, stream>>>(att, dw1, db1, dw2, db2, dw3, db3, (float*)d_out);
}

// Round 4
// 1625.305 us; speedup vs baseline: 2.4428x; 2.4428x over previous
//
#include <hip/hip_runtime.h>
#include <cstdint>

constexpr int B    = 256;
constexpr int S    = 33;
constexpr int D    = 42;
constexpr int H    = 128;
constexpr int HFF  = 256;
constexpr int T    = 20;
constexpr int NSTEP = S - 1;   // 32
constexpr int DP   = D / 2;    // 21 f16 d-pairs
constexpr int AW   = 16384;    // A dwords per sample (128 e-pairs x 128 h)
#define BN_SCALE 0.9999950000374997f

typedef _Float16 h2v __attribute__((ext_vector_type(2)));
union UH2 { uint32_t u; h2v h; };

__device__ __forceinline__ float fdot2u(uint32_t a, uint32_t b, float c) {
    UH2 x, y; x.u = a; y.u = b;
    return __builtin_amdgcn_fdot2(x.h, y.h, c, false);
}
__device__ __forceinline__ uint32_t packh2(float a, float b) {
    UH2 u; u.h = h2v{(_Float16)a, (_Float16)b}; return u.u;
}
__device__ __forceinline__ float gelu_exact(float x) {
    return 0.5f * x * (1.0f + erff(x * 0.70710678118654752f));
}

// ---------------------------------------------------------------------------
// One-time weight packing (f16 pairs, quad-friendly layouts).
//  w0q[(ipb*256+j)*4+k] = pair(w0[2*(4ipb+k)][j], w0[2*(4ipb+k)+1][j])  ipb<16
//  w1q/w2q: same with ipb<32
//  wq[u*84 + el*21 + dp], u = ib*256 + t, t->(h=t>>1, half=t&1),
//      e = 8*ib + 4*half + el : pair(w3[e][h*D+2dp], w3[e][h*D+2dp+1])
//  b3p[h*21+dp] = pair(b3[h*42+2dp], b3[h*42+2dp+1])
// ---------------------------------------------------------------------------
__global__ void pack_kernel(const float* __restrict__ w0, const float* __restrict__ w1,
                            const float* __restrict__ w2, const float* __restrict__ w3,
                            const float* __restrict__ b3,
                            uint32_t* __restrict__ w0q, uint32_t* __restrict__ w1q,
                            uint32_t* __restrict__ w2q, uint32_t* __restrict__ wq,
                            uint32_t* __restrict__ b3p) {
    int idx = blockIdx.x * 256 + threadIdx.x;
    if (idx < 16 * 256 * 4) {
        int k = idx & 3, j = (idx >> 2) & 255, ipb = idx >> 10;
        int ip = 4 * ipb + k;
        w0q[idx] = packh2(w0[(2 * ip) * HFF + j], w0[(2 * ip + 1) * HFF + j]);
    }
    if (idx < 32 * 256 * 4) {
        int k = idx & 3, j = (idx >> 2) & 255, ipb = idx >> 10;
        int ip = 4 * ipb + k;
        w1q[idx] = packh2(w1[(2 * ip) * HFF + j], w1[(2 * ip + 1) * HFF + j]);
        w2q[idx] = packh2(w2[(2 * ip) * HFF + j], w2[(2 * ip + 1) * HFF + j]);
    }
    if (idx < H * DP) {
        int hh = idx / DP, dp = idx % DP;
        b3p[idx] = packh2(b3[hh * D + 2 * dp], b3[hh * D + 2 * dp + 1]);
    }
    if (idx < 8192 * 84) {
        int u = idx / 84, r = idx % 84;
        int ib = u >> 8, t = u & 255;
        int h = t >> 1, half = t & 1;
        int el = r / 21, dp = r % 21;
        int e = 8 * ib + 4 * half + el;
        wq[idx] = packh2(w3[e * (H * D) + h * D + 2 * dp],
                         w3[e * (H * D) + h * D + 2 * dp + 1]);
    }
}

// ---------------------------------------------------------------------------
// Encoder (z0), dxdt f16 pairs, dt.  One block per sample, 128 threads.
// ---------------------------------------------------------------------------
__global__ void prep_kernel(const float* __restrict__ path, const float* __restrict__ ts,
                            const float* __restrict__ ew1, const float* __restrict__ eb1,
                            const float* __restrict__ eg1, const float* __restrict__ ebe1,
                            const float* __restrict__ ew2, const float* __restrict__ eb2,
                            const float* __restrict__ eg2, const float* __restrict__ ebe2,
                            float* __restrict__ zbuf, uint32_t* __restrict__ dxdtp,
                            float* __restrict__ dtb) {
    __shared__ float x0[D], hb[H];
    int b = blockIdx.x, tid = threadIdx.x;
    if (tid < D) x0[tid] = path[b * S * D + tid];
    __syncthreads();
    {
        float acc = eb1[tid];
        for (int d = 0; d < D; ++d) acc += x0[d] * ew1[d * H + tid];
        hb[tid] = gelu_exact(acc * (eg1[tid] * BN_SCALE) + ebe1[tid]);
    }
    __syncthreads();
    {
        float acc = eb2[tid];
        for (int i = 0; i < H; ++i) acc += hb[i] * ew2[i * H + tid];
        zbuf[b * H + tid] = acc * (eg2[tid] * BN_SCALE) + ebe2[tid];
    }
    for (int idx = tid; idx < NSTEP * DP; idx += 128) {
        int s = idx / DP, j = idx % DP;
        float dtv = ts[s + 1] - ts[s];
        int base = b * S * D + s * D + 2 * j;
        float v0 = (path[base + D] - path[base]) / dtv;
        float v1 = (path[base + D + 1] - path[base + 1]) / dtv;
        dxdtp[(s * B + b) * DP + j] = packh2(v0, v1);
    }
    if (b == 0 && tid < NSTEP) dtb[tid] = ts[tid + 1] - ts[tid];
}

// ---------------------------------------------------------------------------
// Fused per-step kernel.
//  blocks [0, eval_blocks): RK4 step s for samples {2c, 2c+1}, c = blockIdx.
//  blocks [eval_blocks, +256): A for step s+1 into Ab_wr (XCD-co-located;
//    writer block idx: x = idx&7 (XCD class), ib = idx>>3; wq via NT loads).
// A layout: Ab[b*AW + ib*512 + h*4 + k], k = sub-e-pair (e = 8ib+2k, 8ib+2k+1).
// ---------------------------------------------------------------------------
__global__ void __launch_bounds__(256) step_kernel(
    const uint32_t* __restrict__ w0q, const uint32_t* __restrict__ w1q,
    const uint32_t* __restrict__ w2q, const uint32_t* __restrict__ wq,
    const uint32_t* __restrict__ b3p, const uint32_t* __restrict__ dxdtp,
    const float* __restrict__ vb0, const float* __restrict__ vg0, const float* __restrict__ vbe0,
    const float* __restrict__ vb1, const float* __restrict__ vg1, const float* __restrict__ vbe1,
    const float* __restrict__ vb2, const float* __restrict__ vg2, const float* __restrict__ vbe2,
    const float* __restrict__ dtb,
    const uint32_t* __restrict__ Ab_rd, uint32_t* __restrict__ Ab_wr,
    float* __restrict__ zbuf, int s, int eval_blocks) {
    int t = threadIdx.x;

    if ((int)blockIdx.x >= eval_blocks) {
        // ----- A writer for step s+1 -----
        int sa = s + 1;
        if (sa >= NSTEP) return;
        int idx = blockIdx.x - eval_blocks;     // 0..255
        int x = idx & 7;                        // XCD class
        int ib = idx >> 3;                      // 0..31
        // thread owns (h = t>>1, half = t&1): e = 8*ib + 4*half + {0..3}
        uint32_t wr[84];
        const uint32_t* wp = wq + (size_t)(ib * 256 + t) * 84;
#pragma unroll
        for (int r = 0; r < 84; ++r) wr[r] = __builtin_nontemporal_load(wp + r);
        uint32_t dstoff = (ib << 9) + 2 * t;    // = ib*512 + h*4 + 2*half
        for (int n = 0; n < 16; ++n) {
#pragma unroll
            for (int par = 0; par < 2; ++par) {
                int b = 16 * n + 2 * x + par;   // (b>>1)&7 == x
                const uint32_t* dxp = dxdtp + (size_t)(sa * B + b) * DP;
                uint32_t dxr[21];
#pragma unroll
                for (int j = 0; j < 21; ++j) dxr[j] = __builtin_nontemporal_load(dxp + j);
                float a0 = 0.f, a1 = 0.f, a2 = 0.f, a3 = 0.f;
#pragma unroll
                for (int j = 0; j < 21; ++j) {
                    a0 = fdot2u(wr[j],      dxr[j], a0);
                    a1 = fdot2u(wr[21 + j], dxr[j], a1);
                    a2 = fdot2u(wr[42 + j], dxr[j], a2);
                    a3 = fdot2u(wr[63 + j], dxr[j], a3);
                }
                uint2 st; st.x = packh2(a0, a1); st.y = packh2(a2, a3);
                *(uint2*)(Ab_wr + (size_t)b * AW + dstoff) = st;
            }
        }
        return;
    }

    // ----- eval: RK4 step s for samples b0, b0+1 -----
    __shared__ uint32_t zzP[2][64];             // z f16 pairs per sample
    __shared__ uint32_t yAp[2][128], yBp[2][128], yCp[2][128];
    int c = blockIdx.x, b0 = 2 * c;
    int sC = t >> 7, hC = t & 127;              // state role
    float hstep = dtb[s];
    float c0b = vb0[t], c0g = vg0[t] * BN_SCALE, c0e = vbe0[t];
    float c1b = vb1[t], c1g = vg1[t] * BN_SCALE, c1e = vbe1[t];
    float c2b = vb2[t], c2g = vg2[t] * BN_SCALE, c2e = vbe2[t];
    int bC = b0 + sC;
    float zf = zbuf[bC * H + hC];
    float bd3;
    {
        const uint32_t* dxC = dxdtp + (size_t)(s * B + bC) * DP;
        const uint32_t* bp = b3p + hC * DP;
        float q0 = 0.f, q1 = 0.f, q2 = 0.f;
#pragma unroll
        for (int j = 0; j < 21; j += 3) {
            q0 = fdot2u(bp[j],     dxC[j],     q0);
            q1 = fdot2u(bp[j + 1], dxC[j + 1], q1);
            q2 = fdot2u(bp[j + 2], dxC[j + 2], q2);
        }
        bd3 = q0 + q1 + q2;
    }
    const uint32_t* Arow = Ab_rd + (size_t)bC * AW + (hC << 2);
    float ksum = 0.f, kcur = 0.f;

    for (int r = 0; r < 4; ++r) {
        float cin = (r == 0) ? 0.f : ((r == 3) ? 1.f : 0.5f);
        float wsm = (r == 1 || r == 2) ? 2.f : 1.f;
        ((_Float16*)zzP)[sC * 128 + hC] = (_Float16)(zf + cin * hstep * kcur);
        __syncthreads();
        // ---- L0: 128 -> 256, thread j = t computes both samples ----
        {
            float a0 = c0b, a1 = c0b;
#pragma unroll
            for (int ipb = 0; ipb < 16; ++ipb) {
                uint4 w = *(const uint4*)(w0q + (((ipb << 8) + t) << 2));
                uint4 z0 = *(const uint4*)&zzP[0][ipb << 2];
                uint4 z1 = *(const uint4*)&zzP[1][ipb << 2];
                a0 = fdot2u(w.x, z0.x, a0); a0 = fdot2u(w.y, z0.y, a0);
                a0 = fdot2u(w.z, z0.z, a0); a0 = fdot2u(w.w, z0.w, a0);
                a1 = fdot2u(w.x, z1.x, a1); a1 = fdot2u(w.y, z1.y, a1);
                a1 = fdot2u(w.z, z1.z, a1); a1 = fdot2u(w.w, z1.w, a1);
            }
            ((_Float16*)yAp)[t]       = (_Float16)gelu_exact(a0 * c0g + c0e);
            ((_Float16*)yAp)[256 + t] = (_Float16)gelu_exact(a1 * c0g + c0e);
        }
        __syncthreads();
        // ---- L1: 256 -> 256 ----
        {
            float a0 = c1b, a1 = c1b;
#pragma unroll
            for (int ipb = 0; ipb < 32; ++ipb) {
                uint4 w = *(const uint4*)(w1q + (((ipb << 8) + t) << 2));
                uint4 y0 = *(const uint4*)&yAp[0][ipb << 2];
                uint4 y1 = *(const uint4*)&yAp[1][ipb << 2];
                a0 = fdot2u(w.x, y0.x, a0); a0 = fdot2u(w.y, y0.y, a0);
                a0 = fdot2u(w.z, y0.z, a0); a0 = fdot2u(w.w, y0.w, a0);
                a1 = fdot2u(w.x, y1.x, a1); a1 = fdot2u(w.y, y1.y, a1);
                a1 = fdot2u(w.z, y1.z, a1); a1 = fdot2u(w.w, y1.w, a1);
            }
            ((_Float16*)yBp)[t]       = (_Float16)gelu_exact(a0 * c1g + c1e);
            ((_Float16*)yBp)[256 + t] = (_Float16)gelu_exact(a1 * c1g + c1e);
        }
        __syncthreads();
        // ---- L2: 256 -> 256 ----
        {
            float a0 = c2b, a1 = c2b;
#pragma unroll
            for (int ipb = 0; ipb < 32; ++ipb) {
                uint4 w = *(const uint4*)(w2q + (((ipb << 8) + t) << 2));
                uint4 y0 = *(const uint4*)&yBp[0][ipb << 2];
                uint4 y1 = *(const uint4*)&yBp[1][ipb << 2];
                a0 = fdot2u(w.x, y0.x, a0); a0 = fdot2u(w.y, y0.y, a0);
                a0 = fdot2u(w.z, y0.z, a0); a0 = fdot2u(w.w, y0.w, a0);
                a1 = fdot2u(w.x, y1.x, a1); a1 = fdot2u(w.y, y1.y, a1);
                a1 = fdot2u(w.z, y1.z, a1); a1 = fdot2u(w.w, y1.w, a1);
            }
            ((_Float16*)yCp)[t]       = (_Float16)gelu_exact(a0 * c2g + c2e);
            ((_Float16*)yCp)[256 + t] = (_Float16)gelu_exact(a1 * c2g + c2e);
        }
        __syncthreads();
        // ---- L3 (state role): kcur[h] = bd3 + sum_p A[bC,p,h] . y2[p] ----
        {
            float q0 = bd3, q1 = 0.f, q2 = 0.f, q3 = 0.f;
#pragma unroll 8
            for (int ib = 0; ib < 32; ++ib) {
                uint4 a = *(const uint4*)(Arow + (ib << 9));
                uint4 y = *(const uint4*)&yCp[sC][ib << 2];
                q0 = fdot2u(a.x, y.x, q0); q1 = fdot2u(a.y, y.y, q1);
                q2 = fdot2u(a.z, y.z, q2); q3 = fdot2u(a.w, y.w, q3);
            }
            kcur = (q0 + q1) + (q2 + q3);
            ksum += wsm * kcur;
        }
        __syncthreads();
    }
    zbuf[bC * H + hC] = zf + hstep * (1.f / 6.f) * ksum;
}

// ---------------------------------------------------------------------------
// attended = (zT@wv+bv)@wo+bo.  One block per sample, 128 threads.
// ---------------------------------------------------------------------------
__global__ void att_kernel(const float* __restrict__ zbuf,
                           const float* __restrict__ wv, const float* __restrict__ bv,
                           const float* __restrict__ wo, const float* __restrict__ bo,
                           float* __restrict__ att) {
    __shared__ float zl[H], v[H];
    int b = blockIdx.x, tid = threadIdx.x;
    zl[tid] = zbuf[b * H + tid];
    __syncthreads();
    {
        float acc = bv[tid];
#pragma unroll 8
        for (int i = 0; i < H; ++i) acc += zl[i] * wv[i * H + tid];
        v[tid] = acc;
    }
    __syncthreads();
    {
        float acc = bo[tid];
#pragma unroll 8
        for (int i = 0; i < H; ++i) acc += v[i] * wo[i * H + tid];
        att[b * H + tid] = acc;
    }
}

// ---------------------------------------------------------------------------
// Decoder: one single-wave block per (t, b).  grid = T*B = 5120.
// ---------------------------------------------------------------------------
__global__ void __launch_bounds__(64) dec_kernel(
    const float* __restrict__ att,
    const float* __restrict__ dw1, const float* __restrict__ db1,
    const float* __restrict__ dw2, const float* __restrict__ db2,
    const float* __restrict__ dw3, const float* __restrict__ db3,
    float* __restrict__ out) {
    int bid = blockIdx.x;
    int t = bid >> 8, b = bid & 255;
    int tid = threadIdx.x;
    __shared__ float al[H], h1l[64];
    al[tid] = att[b * H + tid];
    al[tid + 64] = att[b * H + tid + 64];
    __syncthreads();
    {
        float acc = db1[t * 64 + tid];
#pragma unroll 8
        for (int i = 0; i < H; ++i) acc += al[i] * dw1[t * H * 64 + i * 64 + tid];
        h1l[tid] = gelu_exact(acc);
    }
    __syncthreads();
    float v = 0.f;
    if (tid < 32) {
        float acc = db2[t * 32 + tid];
#pragma unroll 8
        for (int i = 0; i < 64; ++i) acc += h1l[i] * dw2[t * 64 * 32 + i * 32 + tid];
        v = gelu_exact(acc) * dw3[t * 32 + tid];
    }
#pragma unroll
    for (int off = 16; off >= 1; off >>= 1) v += __shfl_down(v, off, 64);
    if (tid == 0) out[b * T + t] = 1.f / (1.f + expf(-(v + db3[t])));
}

// ---------------------------------------------------------------------------
extern "C" void kernel_launch(void* const* d_in, const int* in_sizes, int n_in,
                              void* d_out, int out_size, void* d_ws, size_t ws_size,
                              hipStream_t stream) {
    const float* path = (const float*)d_in[0];
    const float* ts   = (const float*)d_in[1];
    const float* ew1  = (const float*)d_in[2];
    const float* eb1  = (const float*)d_in[3];
    const float* eg1  = (const float*)d_in[4];
    const float* ebe1 = (const float*)d_in[5];
    const float* ew2  = (const float*)d_in[6];
    const float* eb2  = (const float*)d_in[7];
    const float* eg2  = (const float*)d_in[8];
    const float* ebe2 = (const float*)d_in[9];
    const float* vw0  = (const float*)d_in[10];
    const float* vb0  = (const float*)d_in[11];
    const float* vg0  = (const float*)d_in[12];
    const float* vbe0 = (const float*)d_in[13];
    const float* vw1  = (const float*)d_in[14];
    const float* vb1  = (const float*)d_in[15];
    const float* vg1  = (const float*)d_in[16];
    const float* vbe1 = (const float*)d_in[17];
    const float* vw2  = (const float*)d_in[18];
    const float* vb2  = (const float*)d_in[19];
    const float* vg2  = (const float*)d_in[20];
    const float* vbe2 = (const float*)d_in[21];
    const float* vw3  = (const float*)d_in[22];
    const float* vb3  = (const float*)d_in[23];
    const float* wv   = (const float*)d_in[24];
    const float* bv   = (const float*)d_in[25];
    const float* wo   = (const float*)d_in[26];
    const float* bo   = (const float*)d_in[27];
    const float* dw1  = (const float*)d_in[28];
    const float* db1  = (const float*)d_in[29];
    const float* dw2  = (const float*)d_in[30];
    const float* db2  = (const float*)d_in[31];
    const float* dw3  = (const float*)d_in[32];
    const float* db3  = (const float*)d_in[33];

    char* ws = (char*)d_ws;
    size_t off = 0;
    auto take = [&](size_t bytes) { char* p = ws + off; off += (bytes + 255) & ~(size_t)255; return p; };
    uint32_t* Ab0   = (uint32_t*)take((size_t)B * AW * 4);          // 16.78 MB
    uint32_t* Ab1   = (uint32_t*)take((size_t)B * AW * 4);          // 16.78 MB
    uint32_t* dxdtp = (uint32_t*)take((size_t)NSTEP * B * DP * 4);  // 688 KB
    float*    dtb   = (float*)take(NSTEP * 4);
    float*    zbuf  = (float*)take((size_t)B * H * 4);
    float*    att   = (float*)take((size_t)B * H * 4);
    uint32_t* w0q   = (uint32_t*)take((size_t)16 * 256 * 4 * 4);
    uint32_t* w1q   = (uint32_t*)take((size_t)32 * 256 * 4 * 4);
    uint32_t* w2q   = (uint32_t*)take((size_t)32 * 256 * 4 * 4);
    uint32_t* wq    = (uint32_t*)take((size_t)8192 * 84 * 4);       // 2.75 MB
    uint32_t* b3p   = (uint32_t*)take((size_t)H * DP * 4);

    pack_kernel<<<(8192 * 84 + 255) / 256, 256, 0, stream>>>(vw0, vw1, vw2, vw3, vb3,
                                                             w0q, w1q, w2q, wq, b3p);
    prep_kernel<<<B, 128, 0, stream>>>(path, ts, ew1, eb1, eg1, ebe1,
                                       ew2, eb2, eg2, ebe2, zbuf, dxdtp, dtb);
    // initial A for step 0 (writer only)
    step_kernel<<<256, 256, 0, stream>>>(w0q, w1q, w2q, wq, b3p, dxdtp,
                                         vb0, vg0, vbe0, vb1, vg1, vbe1, vb2, vg2, vbe2,
                                         dtb, Ab1, Ab0, zbuf, -1, 0);
    for (int s = 0; s < NSTEP; ++s) {
        const uint32_t* rd = (s & 1) ? Ab1 : Ab0;
        uint32_t*       wr = (s & 1) ? Ab0 : Ab1;
        int grid = (s < NSTEP - 1) ? (128 + 256) : 128;
        step_kernel<<<grid, 256, 0, stream>>>(w0q, w1q, w2q, wq, b3p, dxdtp,
                                              vb0, vg0, vbe0, vb1, vg1, vbe1, vb2, vg2, vbe2,
                                              dtb, rd, wr, zbuf, s, 128);
    }
    att_kernel<<<B, 128, 0, stream>>>(zbuf, wv, bv, wo, bo, att);
    dec_kernel<<<T * B, 64, 0, stream>>>(att, dw1, db1, dw2, db2, dw3, db3, (float*)d_out);
}